// Round 13
// baseline (607.694 us; speedup 1.0000x reference)
//
#include <hip/hip_runtime.h>
#include <cstddef>

// MultiStepLinearRNN: 2-layer linear RNN, T=512 encode + F=32 decode.
// R13 = R12 (29-group plan, 64x32 tiles, GRID 1024, counted-vmcnt chunk loop
// -- PROVEN 548us) with ONE mechanism change: dynamic-state READS are plain
// L2-cached (the 8-16x B re-read amplification was saturating the LLC-direct
// path at ~2.6TB/s); dynamic WRITES stay sc0/sc1 write-through (no dirty L2),
// and each grid barrier ends with buffer_inv sc0 sc1 (clean L2/L1 invalidate)
// for cross-XCD freshness. fp16 MFMA 16x16x32, fp32 accum.

typedef _Float16 f16;
typedef _Float16 f16x8 __attribute__((ext_vector_type(8)));
typedef _Float16 f16x4 __attribute__((ext_vector_type(4)));
typedef float f32x4 __attribute__((ext_vector_type(4)));

#define NCTR 32
#define LDA  136     // LDS row stride in halves (128 + 8 pad)
#define ALPHAF 0.00390625f   // 2^-8 decode state pre-scale
#define RALPHAF 256.0f
#define DIN 128
#define NF 32

// ---------------- workspace layout (f16 element offsets) ----------------
constexpr int SZ = 512*512;
constexpr int off_cat   = 0;         // [512][640] = A0|Wx0 row-major
constexpr int off_catA1 = 327680;    // [512][1024] = A1|Wx1 row-major
constexpr int off_A0c   = 851968;    // A0 col-major [512c][512]
constexpr int off_A1c   = 1114112;
constexpr int off_Wpr   = 1376256;   // [128][512]
constexpr int off_Wpc   = 1441792;   // [512c][128]
constexpr int off_Gr    = 1507328;   // G row-major [1024][1024]
constexpr int off_Gc    = 2555904;   // G col-major
constexpr int off_P0    = 3604480;   // A0 powers: 3 (row,col) slot pairs
constexpr int off_P1    = 5177344;   // A1 powers: 3 slot pairs
constexpr int GPr       = 6750208;   // G-power slot P row
constexpr int GPc       = 7798784;
constexpr int GQr       = 8847360;
constexpr int GQc       = 9895936;
constexpr int off_Xin   = 10944512;  // [32768c][128], col = t*64+b
constexpr int BA        = 15138816;  // 4 big buffers [4096c][512]
constexpr int BB        = 17235968;
constexpr int BC        = 19333120;
constexpr int BD        = 21430272;
constexpr int off_S     = 23527424;  // decode states [2048c][1024]
constexpr int off_Dc    = 25624576;  // b_1 [64c][1024]
constexpr int off_Db    = 25690112;  // b_2,4,8,16: 4 x [64c][1024]
constexpr int off_b0h   = 25952256;
constexpr int off_b1h   = 25952768;
constexpr int off_b0ah  = 25953280;
constexpr int off_b1ah  = 25953792;
constexpr int off_bph   = 25954304;
constexpr int off_bpX   = 25954432;  // bp replicated [64c][128]
constexpr int off_ctr   = 25962624;  // 2048 u32 barrier state
// end = 25966720 f16 = 49.5 MiB
// Coherence protocol: every kernel-written (dynamic) buffer is STORED with
// sc0 sc1 (write-through to LLC, bypassing L1/L2 -> no dirty lines), READ
// with plain cached loads, and L1/L2 are clean-invalidated at each barrier.

constexpr int P0r(int s){ return off_P0 + s*524288; }
constexpr int P0c(int s){ return off_P0 + s*524288 + 262144; }
constexpr int P1r(int s){ return off_P1 + s*524288; }
constexpr int P1c(int s){ return off_P1 + s*524288 + 262144; }
constexpr int Bb(int k){ return k==0 ? off_Dc : off_Db + (k-1)*65536; }

// ---------------- op table ----------------
struct Op {
  int type;
  int m_off, m_rstride, rows, cols;
  int k1, x1_off, x1_ks, x1_s1, x1_s2;
  int k2, x2_off, x2_ks, x2_s1, x2_s2;
  int add_off, add_ks, add_s1, add_s2;
  int bias_off; float scale;
  int y_off, y_ks, y_s1, y_s2;
  int yt_off, yt_rstride;
  int out32, tile_base;
};
constexpr int MAXOPS = 80, MAXG = 32;
struct Plan { Op ops[MAXOPS]; int gstart[MAXG+1]; int gtiles[MAXG]; int nops, ng; };

constexpr Op mko() {
  Op o{};
  o.type=0; o.m_off=0; o.m_rstride=512; o.rows=512; o.cols=512;
  o.k1=512; o.x1_off=0; o.x1_ks=512; o.x1_s1=64; o.x1_s2=0;
  o.k2=0; o.x2_off=0; o.x2_ks=512; o.x2_s1=64; o.x2_s2=0;
  o.add_off=-1; o.add_ks=512; o.add_s1=64; o.add_s2=0;
  o.bias_off=-1; o.scale=1.0f;
  o.y_off=-1; o.y_ks=512; o.y_s1=64; o.y_s2=0;
  o.yt_off=-1; o.yt_rstride=512; o.out32=0; o.tile_base=0;
  return o;
}
// 64x32 tiles
constexpr int op_ntiles(const Op& o){ return (o.rows>>6)*(o.cols>>5); }

struct Builder { Plan p{}; int nops=0, ng=0, gtile=0; };
constexpr void push(Builder& b, Op o){ o.tile_base=b.gtile; b.gtile+=op_ntiles(o); b.p.ops[b.nops++]=o; }
constexpr void endg(Builder& b){ b.p.gtiles[b.ng]=b.gtile; b.ng++; b.p.gstart[b.ng]=b.nops; b.gtile=0; }

constexpr Op SQ2(int m,int mrs,int x1c,int yc,int yr){
  Op o=mko(); o.m_off=m; o.m_rstride=mrs; o.x1_off=x1c; o.y_off=yc; o.yt_off=yr; return o; }
constexpr Op SQG(int mr,int xc,int yc,int yr){
  Op o=mko(); o.rows=1024; o.cols=1024; o.k1=1024; o.m_off=mr; o.m_rstride=1024;
  o.x1_off=xc; o.x1_ks=1024; o.y_off=yc; o.y_ks=1024; o.yt_off=yr; o.yt_rstride=1024; return o; }
constexpr Op P2S(int s){
  Op o=mko(); o.cols=4096; o.bias_off=off_b0h;
  o.k2=128; o.x2_off=off_Xin; o.x2_ks=128; o.x2_s1=512; o.x2_s2=(s-1)*64;
  o.y_off=(s&1)?BA:BB;
  if (s==1){ o.m_off=off_cat+512; o.m_rstride=640; o.k1=0; }
  else { o.m_off=off_cat; o.m_rstride=640; o.k1=512; o.x1_off=(s&1)?BB:BA; }
  return o; }
constexpr Op HS(int s){
  Op o=mko(); o.m_off=off_cat; o.m_rstride=640; o.cols=4096;
  o.k1=512; o.x1_off=(s&1)?BC:BB;
  o.k2=128; o.x2_off=off_Xin; o.x2_ks=128; o.x2_s1=512; o.x2_s2=(s-1)*64;
  o.bias_off=off_b0h; o.y_off=(s&1)?BB:BC; return o; }
constexpr Op RS(int s){
  Op o=mko(); o.cols=4096; o.bias_off=off_b1h;
  if (s==1){ o.m_off=off_catA1+512; o.m_rstride=1024; o.k1=512; o.x1_off=BB; o.y_off=BD; }
  else { o.m_off=off_catA1; o.m_rstride=1024; o.k1=512; o.x1_off=(s&1)?BA:BD;
         o.k2=512; o.x2_off=(s&1)?BB:BC; o.x2_ks=512; o.x2_s1=64; o.x2_s2=0;
         o.y_off=(s&1)?BD:BA; }
  return o; }
constexpr Op SCAN(int m,int d,int inb,int outb){
  Op o=mko(); o.m_off=m; o.cols=4096-d*64; o.x1_off=inb;
  o.add_off=inb; o.add_s2=d*64; o.y_off=outb; o.y_s2=d*64; return o; }
constexpr Op SCOPY(int d,int inb,int outb){
  Op o=mko(); o.k1=0; o.cols=d*64; o.add_off=inb; o.y_off=outb; return o; }
constexpr Op FOLDL(int m,int cols,int inb,int outb){
  Op o=mko(); o.m_off=m; o.cols=cols; o.x1_off=inb; o.x1_s1=128;
  o.add_off=inb; o.add_s1=128; o.add_s2=64; o.y_off=outb; return o; }
constexpr Op DECA(int k,int moff){
  Op o=mko(); int m=1<<k;
  o.rows=1024; o.cols=m*64; o.k1=1024; o.m_off=moff; o.m_rstride=1024;
  o.x1_off=off_S; o.x1_ks=1024; o.bias_off=Bb(k);
  o.y_off=off_S; o.y_ks=1024; o.y_s2=m*64; return o; }
constexpr Op DECB(int k,int moff){
  Op o=mko(); o.rows=1024; o.cols=64; o.k1=1024; o.m_off=moff; o.m_rstride=1024;
  o.x1_off=Bb(k); o.x1_ks=1024; o.bias_off=Bb(k);
  o.y_off=Bb(k+1); o.y_ks=1024; return o; }

constexpr Plan build_plan() {
  Builder b{}; b.p.gstart[0]=0;
  // g0: A0^2, A1^2, E, c0, P2 s1
  push(b, SQ2(off_cat,640,off_A0c,P0c(0),P0r(0)));
  push(b, SQ2(off_catA1,1024,off_A1c,P1c(0),P1r(0)));
  { Op o=mko(); o.m_off=off_cat+512; o.m_rstride=640; o.k1=128; o.x1_off=off_Wpc; o.x1_ks=128;
    o.y_off=off_Gc+512*1024; o.y_ks=1024; o.yt_off=off_Gr+512; o.yt_rstride=1024; push(b,o); } // E
  { Op o=mko(); o.m_off=off_cat+512; o.m_rstride=640; o.k1=128; o.x1_off=off_bpX; o.x1_ks=128;
    o.cols=64; o.bias_off=off_b0ah; o.scale=ALPHAF; o.y_off=off_Dc; o.y_ks=1024; push(b,o); } // c0
  push(b, P2S(1)); endg(b);
  // g1: A0^4, A1^4, F10, c1, P2 s2
  push(b, SQ2(P0r(0),512,P0c(0),P0c(1),P0r(1)));
  push(b, SQ2(P1r(0),512,P1c(0),P1c(1),P1r(1)));
  { Op o=mko(); o.m_off=off_catA1+512; o.m_rstride=1024; o.x1_off=off_A0c;
    o.y_off=off_Gc+512; o.y_ks=1024; o.yt_off=off_Gr+512*1024; o.yt_rstride=1024; push(b,o); } // F10
  { Op o=mko(); o.m_off=off_catA1+512; o.m_rstride=1024; o.x1_off=off_Dc; o.x1_ks=1024;
    o.cols=64; o.bias_off=off_b1ah; o.y_off=off_Dc+512; o.y_ks=1024; push(b,o); } // c1
  push(b, P2S(2)); endg(b);
  // g2: A0^8, A1^8, F11, P2 s3
  push(b, SQ2(P0r(1),512,P0c(1),P0c(2),P0r(2)));
  push(b, SQ2(P1r(1),512,P1c(1),P1c(2),P1r(2)));
  { Op o=mko(); o.m_off=off_catA1+512; o.m_rstride=1024; o.x1_off=off_Gc+512*1024; o.x1_ks=1024;
    o.add_off=off_A1c; o.y_off=off_Gc+512*1024+512; o.y_ks=1024;
    o.yt_off=off_Gr+512*1024+512; o.yt_rstride=1024; push(b,o); } // F11 = Wx1 E + A1
  push(b, P2S(3)); endg(b);
  // g3: A0^16, A1^16, P2 s4
  push(b, SQ2(P0r(2),512,P0c(2),P0c(0),P0r(0)));
  push(b, SQ2(P1r(2),512,P1c(2),P1c(0),P1r(0)));
  push(b, P2S(4)); endg(b);
  // g4: A0^32, A1^32, P2 s5
  push(b, SQ2(P0r(0),512,P0c(0),P0c(1),P0r(1)));
  push(b, SQ2(P1r(0),512,P1c(0),P1c(1),P1r(1)));
  push(b, P2S(5)); endg(b);
  // g5: P2 s6 + G^2
  push(b, P2S(6));
  push(b, SQG(off_Gr, off_Gc, GPc, GPr)); endg(b);
  // g6,g7: P2 s7, s8   (g = BB)
  push(b, P2S(7)); endg(b);
  push(b, P2S(8)); endg(b);
  // g8..g10: scan levels (A0^8, A0^16, A0^32) -> final in BA
  push(b, SCAN(P0r(2), 1, BB, BA)); push(b, SCOPY(1, BB, BA)); endg(b);
  push(b, SCAN(P0r(0), 2, BA, BB)); push(b, SCOPY(2, BA, BB)); endg(b);
  push(b, SCAN(P0r(1), 4, BB, BA)); push(b, SCOPY(4, BB, BA)); endg(b);
  // g11: h1 (shifted chunk-start read) -> BB
  { Op o=mko(); o.m_off=off_cat; o.m_rstride=640; o.cols=4032; o.k1=512; o.x1_off=BA;
    o.k2=128; o.x2_off=off_Xin; o.x2_ks=128; o.x2_s1=512; o.x2_s2=512;
    o.bias_off=off_b0h; o.y_off=BB; o.y_s2=64; push(b,o); }
  { Op o=mko(); o.m_off=off_cat+512; o.m_rstride=640; o.cols=64; o.k1=0;
    o.k2=128; o.x2_off=off_Xin; o.x2_ks=128; o.x2_s1=512; o.x2_s2=0;
    o.bias_off=off_b0h; o.y_off=BB; push(b,o); }
  endg(b);
  // g12..g18: {h(s+1), r(s)} for s=1..7
  for (int s=1; s<=7; ++s){ push(b, HS(s+1)); push(b, RS(s)); endg(b); }
  // g19: r8 + h0_final -> S top
  push(b, RS(8));
  { Op o=mko(); o.k1=0; o.cols=64; o.add_off=BC; o.add_s2=4032; o.scale=ALPHAF;
    o.y_off=off_S; o.y_ks=1024; push(b,o); }
  endg(b);
  // g20,g21: fold l0 (A1^8), l1 (A1^16)
  push(b, FOLDL(P1r(2), 2048, BA, BB)); endg(b);
  push(b, FOLDL(P1r(0), 1024, BB, BC)); endg(b);
  // g22: h1_final = v15 + A1^32 v14 -> S bottom
  { Op o=mko(); o.m_off=P1r(1); o.cols=64; o.x1_off=BC; o.x1_s2=896;
    o.add_off=BC; o.add_s2=960; o.scale=ALPHAF;
    o.y_off=off_S+512; o.y_ks=1024; push(b,o); }
  endg(b);
  // g23..g27: decode doubling with JIT G squarings
  push(b, DECA(0, off_Gr)); push(b, DECB(0, off_Gr)); endg(b);
  push(b, DECA(1, GPr)); push(b, DECB(1, GPr)); push(b, SQG(GPr,GPc,GQc,GQr)); endg(b);
  push(b, DECA(2, GQr)); push(b, DECB(2, GQr)); push(b, SQG(GQr,GQc,GPc,GPr)); endg(b);
  push(b, DECA(3, GPr)); push(b, DECB(3, GPr)); push(b, SQG(GPr,GPc,GQc,GQr)); endg(b);
  push(b, DECA(4, GQr)); endg(b);
  // g28: output p_t = 256 * (Wp h1_t) + bp
  { Op o=mko(); o.m_off=off_Wpr; o.rows=128; o.cols=2048; o.x1_off=off_S+512; o.x1_ks=1024;
    o.bias_off=off_bph; o.scale=RALPHAF; o.out32=1; push(b,o); }
  endg(b);
  b.p.nops=b.nops; b.p.ng=b.ng;
  return b.p;
}
static constexpr Plan h_plan = build_plan();
__device__ __constant__ Plan d_plan = h_plan;

// ---------------- async load primitives (plain cached, NO waitcnt) ---------
__device__ inline void issueA4(const f16* p, f16x8 (&r)[4]) {
  asm volatile(
    "global_load_dwordx4 %0, %4, off\n\t"
    "global_load_dwordx4 %1, %4, off offset:16\n\t"
    "global_load_dwordx4 %2, %4, off offset:32\n\t"
    "global_load_dwordx4 %3, %4, off offset:48"
    : "=&v"(r[0]), "=&v"(r[1]), "=&v"(r[2]), "=&v"(r[3])
    : "v"(p) : "memory");
}
__device__ inline void issueB2(const f16* p, f16x8 (&r)[2]) {
  asm volatile(
    "global_load_dwordx4 %0, %2, off\n\t"
    "global_load_dwordx4 %1, %2, off offset:16"
    : "=&v"(r[0]), "=&v"(r[1]) : "v"(p) : "memory");
}
__device__ inline void issue_ld8(const f16* p, f16x4& r) {
  asm volatile("global_load_dwordx2 %0, %1, off"
               : "=&v"(r) : "v"(p) : "memory");
}
// ---------------- write-through (LLC) store primitives ---------------------
__device__ inline void st8_cc(f16* p, f16x4 v) {
  asm volatile("global_store_dwordx2 %0, %1, off sc0 sc1" :: "v"(p), "v"(v) : "memory");
}
__device__ inline void st2_cc(f16* p, f16 v) {
  unsigned d = __builtin_bit_cast(unsigned short, v);
  asm volatile("global_store_short %0, %1, off sc0 sc1" :: "v"(p), "v"(d) : "memory");
}
__device__ inline unsigned ld_u32_cc(const unsigned* p) {
  unsigned r;
  asm volatile("global_load_dword %0, %1, off sc0 sc1\n\ts_waitcnt vmcnt(0)"
               : "=&v"(r) : "v"(p) : "memory");
  return r;
}
__device__ inline void st_u32_cc(unsigned* p, unsigned v) {
  asm volatile("global_store_dword %0, %1, off sc0 sc1" :: "v"(p), "v"(v) : "memory");
}
// clean invalidate of this XCD's L1+L2 (no writeback: all dynamic stores are
// write-through, so L2 holds no dirty kernel data)
__device__ inline void l2_inv() {
  asm volatile("buffer_inv sc0 sc1\n\ts_waitcnt vmcnt(0)" ::: "memory");
}

// ------- grid barrier: 32 arrival + 32 release flag lines + L2 inv ---------
__device__ inline void grid_barrier(unsigned* ctrs, unsigned epoch) {
  __syncthreads();   // full drain: all stores issued & counted before arrival
  if (threadIdx.x == 0)
    __hip_atomic_fetch_add(&ctrs[(blockIdx.x & (NCTR-1))*32], 1u,
                           __ATOMIC_RELAXED, __HIP_MEMORY_SCOPE_AGENT);
  if (blockIdx.x == 0) {
    if (threadIdx.x < NCTR) {
      const unsigned tgt = epoch * (gridDim.x / NCTR);
      while (ld_u32_cc(&ctrs[threadIdx.x*32]) < tgt)
        __builtin_amdgcn_s_sleep(1);
    }
    __syncthreads();
    if (threadIdx.x < NCTR)
      st_u32_cc(&ctrs[(NCTR + threadIdx.x)*32], epoch);
  } else if (threadIdx.x == 0) {
    const unsigned fl = (NCTR + (blockIdx.x & (NCTR-1)))*32;
    while (ld_u32_cc(&ctrs[fl]) < epoch)
      __builtin_amdgcn_s_sleep(1);
  }
  // all producers' write-through stores are in the LLC; drop stale clean
  // copies from this XCD's caches before the next group reads them.
  if (threadIdx.x == 0) l2_inv();
  __syncthreads();
}

// ---------------- GEMM tile machinery (64x32 tiles) ----------------
__device__ inline void chunk_srcs(const Op& o, const f16* w, int r0, int c0, int kc,
                                  const f16*& pa, const f16*& pb) {
  const int tid = threadIdx.x;
  pa = w + o.m_off + (size_t)(r0 + (tid>>2)) * o.m_rstride + kc + (tid&3)*32;
  int C = c0 + (tid>>3);
  int xo, xks, xs1, xs2, xk;
  if (kc < o.k1) { xo=o.x1_off; xks=o.x1_ks; xs1=o.x1_s1; xs2=o.x1_s2; xk=kc; }
  else           { xo=o.x2_off; xks=o.x2_ks; xs1=o.x2_s1; xs2=o.x2_s2; xk=kc-o.k1; }
  int xcol = xs1*(C>>6) + (C&63) + xs2;
  pb = w + xo + (size_t)xcol*xks + xk + (tid&7)*16;
}

__device__ inline void st_lds(f16* lsA, f16* lsB, const f16x8 (&ra)[4], const f16x8 (&rb)[2]) {
  const int tid = threadIdx.x;
  f16* da = lsA + (tid>>2)*LDA + (tid&3)*32;
#pragma unroll
  for (int i=0;i<4;++i) *(f16x8*)(da + i*8) = ra[i];
  f16* db = lsB + (tid>>3)*LDA + (tid&7)*16;
#pragma unroll
  for (int i=0;i<2;++i) *(f16x8*)(db + i*8) = rb[i];
}

__device__ inline void mfma_lds(const f16* lsA, const f16* lsB, f32x4 (&acc)[2]) {
  const int tid = threadIdx.x, lane = tid & 63, wid = tid >> 6;
  const int ko = (lane >> 4) * 8, rl = lane & 15;
#pragma unroll
  for (int kb = 0; kb < 4; ++kb) {
    f16x8 a = *(const f16x8*)(lsA + (wid*16 + rl) * LDA + kb*32 + ko);
#pragma unroll
    for (int n = 0; n < 2; ++n) {
      f16x8 bb = *(const f16x8*)(lsB + (n*16 + rl) * LDA + kb*32 + ko);
      acc[n] = __builtin_amdgcn_mfma_f32_16x16x32_f16(a, bb, acc[n], 0, 0, 0);
    }
  }
}

// Raw-barrier chunk step (T4): lgkmcnt-only around s_barrier, counted vmcnt
// keeps up to 2 newer chunks' loads in flight ACROSS the barriers.
#define CH_STEP(c_, raX, rbX)                                                  \
  do {                                                                         \
    asm volatile("s_waitcnt lgkmcnt(0)" ::: "memory");                         \
    __builtin_amdgcn_s_barrier();                                              \
    __builtin_amdgcn_sched_barrier(0);                                         \
    int rem_ = nch - 1 - (c_);                                                 \
    if (rem_ >= 2)      asm volatile("s_waitcnt vmcnt(12)" ::: "memory");      \
    else if (rem_ == 1) asm volatile("s_waitcnt vmcnt(6)"  ::: "memory");      \
    else                asm volatile("s_waitcnt vmcnt(0)"  ::: "memory");      \
    __builtin_amdgcn_sched_barrier(0);                                         \
    st_lds(lsA, lsB, raX, rbX);                                                \
    asm volatile("s_waitcnt lgkmcnt(0)" ::: "memory");                         \
    __builtin_amdgcn_s_barrier();                                              \
    __builtin_amdgcn_sched_barrier(0);                                         \
    if ((c_) + 3 < nch) {                                                      \
      chunk_srcs(o, w, r0, c0, ((c_)+3)*128, pa, pb);                          \
      issueA4(pa, raX); issueB2(pb, rbX);                                      \
    }                                                                          \
    mfma_lds(lsA, lsB, acc);                                                   \
  } while (0)

__device__ void run_tile(const Op& o, int local, f16* w, float* out, f16* lsA, f16* lsB) {
  int nct = o.cols >> 5;
  int rg = local / nct, ct = local - rg * nct;
  int r0 = rg << 6, c0 = ct << 5;
  f32x4 acc[2];
  acc[0] = f32x4{0.f,0.f,0.f,0.f}; acc[1] = f32x4{0.f,0.f,0.f,0.f};
  int nch = (o.k1 + o.k2) >> 7;
  if (nch > 0) {
    const f16 *pa, *pb;
    f16x8 ra0[4], rb0[2], ra1[4], rb1[2], ra2[4], rb2[2];
    chunk_srcs(o, w, r0, c0, 0, pa, pb);
    issueA4(pa, ra0); issueB2(pb, rb0);
    if (nch > 1) { chunk_srcs(o, w, r0, c0, 128, pa, pb);
                   issueA4(pa, ra1); issueB2(pb, rb1); }
    if (nch > 2) { chunk_srcs(o, w, r0, c0, 256, pa, pb);
                   issueA4(pa, ra2); issueB2(pb, rb2); }
    for (int c = 0; c < nch; c += 3) {
      CH_STEP(c, ra0, rb0);
      if (c + 1 < nch) CH_STEP(c+1, ra1, rb1);
      if (c + 2 < nch) CH_STEP(c+2, ra2, rb2);
    }
  }
  const int tid = threadIdx.x, lane = tid & 63, wid = tid >> 6;
  const int q4 = (lane >> 4) * 4, cl = lane & 15;
  const int r = r0 + wid*16 + q4;
  // ---- batched epilogue operand loads (issue all async, wait once) ----
  f16x4 addv[2], biasv;
  bool pend = false;
  if (o.add_off >= 0) {
#pragma unroll
    for (int n = 0; n < 2; ++n) {
      int C = c0 + n*16 + cl;
      int acol = o.add_s1 * (C>>6) + (C&63) + o.add_s2;
      const f16* ap = w + o.add_off + (size_t)acol * o.add_ks + r;
      issue_ld8(ap, addv[n]); pend = true;
    }
  }
  if (o.bias_off >= 0) {
    const f16* bp2 = w + o.bias_off + r;
    issue_ld8(bp2, biasv); pend = true;
  }
  if (pend) asm volatile("s_waitcnt vmcnt(0)" ::: "memory");
#pragma unroll
  for (int n = 0; n < 2; ++n) {
    int C = c0 + n*16 + cl;
    f32x4 v = acc[n];
    if (o.add_off >= 0) {
      v[0]+=(float)addv[n][0]; v[1]+=(float)addv[n][1];
      v[2]+=(float)addv[n][2]; v[3]+=(float)addv[n][3];
    }
    v[0]*=o.scale; v[1]*=o.scale; v[2]*=o.scale; v[3]*=o.scale;
    if (o.bias_off >= 0) {
      v[0]+=(float)biasv[0]; v[1]+=(float)biasv[1];
      v[2]+=(float)biasv[2]; v[3]+=(float)biasv[3];
    }
    if (o.y_off >= 0) {
      int ycol = o.y_s1 * (C>>6) + (C&63) + o.y_s2;
      f16* yp = w + o.y_off + (size_t)ycol * o.y_ks + r;
      f16x4 h; h[0]=(f16)v[0]; h[1]=(f16)v[1]; h[2]=(f16)v[2]; h[3]=(f16)v[3];
      st8_cc(yp, h);
    }
    if (o.yt_off >= 0) {
      f16* tp = w + o.yt_off;
      st2_cc(tp + (size_t)(r+0)*o.yt_rstride + C, (f16)v[0]);
      st2_cc(tp + (size_t)(r+1)*o.yt_rstride + C, (f16)v[1]);
      st2_cc(tp + (size_t)(r+2)*o.yt_rstride + C, (f16)v[2]);
      st2_cc(tp + (size_t)(r+3)*o.yt_rstride + C, (f16)v[3]);
    }
    if (o.out32) {
      float* op2 = out + (size_t)(C & 63) * (NF*DIN) + (size_t)(C >> 6) * DIN + r;
      op2[0]=v[0]; op2[1]=v[1]; op2[2]=v[2]; op2[3]=v[3];
    }
  }
}

__global__ __launch_bounds__(256, 4) void rnn_main(f16* w, float* out) {
  __shared__ f16 lsA[64*LDA];
  __shared__ f16 lsB[32*LDA];
  unsigned* ctrs = (unsigned*)(w + off_ctr);
  const int wg = blockIdx.x;
  const int stride = gridDim.x;
  const int ng = d_plan.ng;
  for (int g = 0; g < ng; ++g) {
    int o0 = d_plan.gstart[g], o1 = d_plan.gstart[g+1];
    int gtot = d_plan.gtiles[g];
    for (int t = wg; t < gtot; t += stride) {
      int oi = o0;
      while (oi + 1 < o1 && t >= d_plan.ops[oi+1].tile_base) ++oi;
      run_tile(d_plan.ops[oi], t - d_plan.ops[oi].tile_base, w, out, lsA, lsB);
    }
    grid_barrier(ctrs, (unsigned)(g + 1));
  }
}

// ---------------- prep ----------------
__global__ void rnn_prep(f16* w, const float* X, const float* Wx0, const float* b0,
    const float* Wh0, const float* d0p, const float* Wx1, const float* b1,
    const float* Wh1, const float* d1p, const float* Wp, const float* bp)
{
  const float d0 = d0p[0], d1 = d1p[0];
  const long n0=512L*640, n1=512L*1024, n2=(long)SZ, n3=(long)SZ, n4=128L*512, n5=512L*128,
             n6=(long)SZ, n7=(long)SZ, n8=32768L*128, n9=512, n10=512, n11=512, n12=512,
             n13=128, n14=64L*128, n15=2048;
  const long total = n0+n1+n2+n3+n4+n5+n6+n7+n8+n9+n10+n11+n12+n13+n14+n15;
  for (long idx = (long)blockIdx.x*blockDim.x + threadIdx.x; idx < total;
       idx += (long)gridDim.x*blockDim.x) {
    long j = idx;
    if (j < n0) { int r=(int)(j/640), c=(int)(j%640);
      w[off_cat+j] = (f16)(c<512 ? d0*Wh0[(long)r*512+c] : Wx0[(long)r*128+(c-512)]); continue; }
    j -= n0;
    if (j < n1) { int r=(int)(j>>10), c=(int)(j&1023);
      w[off_catA1+j] = (f16)(c<512 ? d1*Wh1[(long)r*512+c] : Wx1[(long)r*512+(c-512)]); continue; }
    j -= n1;
    if (j < n2) { int c=(int)(j>>9), r=(int)(j&511); w[off_A0c+j] = (f16)(d0*Wh0[(long)r*512+c]); continue; }
    j -= n2;
    if (j < n3) { int c=(int)(j>>9), r=(int)(j&511); w[off_A1c+j] = (f16)(d1*Wh1[(long)r*512+c]); continue; }
    j -= n3;
    if (j < n4) { w[off_Wpr+j] = (f16)Wp[j]; continue; }
    j -= n4;
    if (j < n5) { int c=(int)(j>>7), k=(int)(j&127); w[off_Wpc+j] = (f16)Wp[(long)k*512+c]; continue; }
    j -= n5;
    if (j < n6) { int r=(int)(j>>9), c=(int)(j&511);
      w[off_Gr + (long)r*1024 + c] = (f16)(d0*Wh0[(long)r*512+c]); continue; }
    j -= n6;
    if (j < n7) { int c=(int)(j>>9), r=(int)(j&511);
      w[off_Gc + (long)c*1024 + r] = (f16)(d0*Wh0[(long)r*512+c]); continue; }
    j -= n7;
    if (j < n8) { int col=(int)(j>>7), d=(int)(j&127); int t=col>>6, bb=col&63;
      w[off_Xin+j] = (f16)X[((long)bb<<16) + ((long)t<<7) + d]; continue; }
    j -= n8;
    if (j < n9) { w[off_b0h+j] = (f16)b0[j]; continue; }  j -= n9;
    if (j < n10){ w[off_b1h+j] = (f16)b1[j]; continue; }  j -= n10;
    if (j < n11){ w[off_b0ah+j] = (f16)(ALPHAF*b0[j]); continue; }  j -= n11;
    if (j < n12){ w[off_b1ah+j] = (f16)(ALPHAF*b1[j]); continue; }  j -= n12;
    if (j < n13){ w[off_bph+j] = (f16)bp[j]; continue; }  j -= n13;
    if (j < n14){ int k=(int)(j&127); w[off_bpX+j] = (f16)bp[k]; continue; }  j -= n14;
    ((unsigned*)(w + off_ctr))[j] = 0u;
  }
}

extern "C" void kernel_launch(void* const* d_in, const int* in_sizes, int n_in,
                              void* d_out, int out_size, void* d_ws, size_t ws_size,
                              hipStream_t stream) {
  (void)in_sizes; (void)n_in; (void)out_size; (void)ws_size; // needs ~50 MB ws
  f16* w = (f16*)d_ws;
  hipLaunchKernelGGL(rnn_prep, dim3(2048), dim3(256), 0, stream,
      w,
      (const float*)d_in[0], (const float*)d_in[1], (const float*)d_in[2],
      (const float*)d_in[3], (const float*)d_in[4], (const float*)d_in[5],
      (const float*)d_in[6], (const float*)d_in[7], (const float*)d_in[8],
      (const float*)d_in[9], (const float*)d_in[10]);
  float* outp = (float*)d_out;
  void* kargs[] = { (void*)&w, (void*)&outp };
  // deterministic grid selection: up to 4 blocks/CU, halving fallback
  int nb = 0;
  hipError_t qe = hipOccupancyMaxActiveBlocksPerMultiprocessor(
      &nb, (const void*)rnn_main, 256, 0);
  int bpc = (qe == hipSuccess && nb >= 1) ? (nb >= 4 ? 4 : (nb >= 2 ? 2 : 1)) : 1;
  int grid = 256 * bpc;
  while (true) {
    hipError_t le = hipLaunchCooperativeKernel((const void*)rnn_main, dim3(grid),
                                               dim3(256), kargs, 0, stream);
    if (le == hipSuccess || grid <= 256) break;
    grid >>= 1;
  }
}

// Round 14
// 552.196 us; speedup vs baseline: 1.1005x; 1.1005x over previous
//
#include <hip/hip_runtime.h>
#include <cstddef>

// MultiStepLinearRNN: 2-layer linear RNN, T=512 encode + F=32 decode.
// R14 = R12 (29-group plan, 64x32 tiles, GRID 1024, counted-vmcnt raw-barrier
// chunk loop -- PROVEN 548us) with ONE mechanism change: WRITE-ONCE buffers
// (Gr,Gc,G2,G4,S,Dc,Db + G8/G16 aliased onto dead Xin) are PLAIN L2-cached
// reads (writes stay sc0/sc1 write-through, so no staleness is possible);
// one-time buffer_inv at the decode boundary clears stale Xin lines. This
// removes ~350-400MB of the ~1.4GB LLC-direct traffic (decode G-matrix
// amplification) that saturated the LLC path at ~2.6TB/s.

typedef _Float16 f16;
typedef _Float16 f16x8 __attribute__((ext_vector_type(8)));
typedef _Float16 f16x4 __attribute__((ext_vector_type(4)));
typedef float f32x4 __attribute__((ext_vector_type(4)));

#define NCTR 32
#define LDA  136     // LDS row stride in halves (128 + 8 pad)
#define ALPHAF 0.00390625f   // 2^-8 decode state pre-scale
#define RALPHAF 256.0f
#define DIN 128
#define NF 32
#define INV_EPOCH 23u   // barrier after g22 (finals) -> decode boundary

// ---------------- workspace layout (f16 element offsets) ----------------
constexpr int SZ = 512*512;
constexpr int off_cat   = 0;         // [512][640] = A0|Wx0 row-major   [static]
constexpr int off_catA1 = 327680;    // [512][1024] = A1|Wx1 row-major  [static]
constexpr int off_A0c   = 851968;    // A0 col-major [512c][512]        [static]
constexpr int off_A1c   = 1114112;   //                                 [static]
constexpr int off_Wpr   = 1376256;   // [128][512]                      [static]
constexpr int off_Wpc   = 1441792;   // [512c][128]                     [static]
constexpr int off_Gr    = 1507328;   // G row-major [1024][1024]  [write-once]
constexpr int off_Gc    = 2555904;   // G col-major               [write-once]
constexpr int off_P0    = 3604480;   // A0 powers: 3 slot pairs   [reused: sc]
constexpr int off_P1    = 5177344;   // A1 powers: 3 slot pairs   [reused: sc]
constexpr int GPr       = 6750208;   // G^2 row                   [write-once]
constexpr int GPc       = 7798784;
constexpr int GQr       = 8847360;   // G^4 row                   [write-once]
constexpr int GQc       = 9895936;
constexpr int off_Xin   = 10944512;  // [32768c][128]; after decode boundary
                                     // ALIASED: G8r/G8c/G16r/G16c (4x1048576)
constexpr int BA        = 15138816;  // 4 big buffers [4096c][512] [reused: sc]
constexpr int BB        = 17235968;
constexpr int BC        = 19333120;
constexpr int BD        = 21430272;
constexpr int off_S     = 23527424;  // decode states [2048c][1024] [write-once]
constexpr int off_Dc    = 25624576;  // b_1 [64c][1024]             [write-once]
constexpr int off_Db    = 25690112;  // b_2..16: 4 x [64c][1024]    [write-once]
constexpr int off_b0h   = 25952256;
constexpr int off_b1h   = 25952768;
constexpr int off_b0ah  = 25953280;
constexpr int off_b1ah  = 25953792;
constexpr int off_bph   = 25954304;
constexpr int off_bpX   = 25954432;  // bp replicated [64c][128]
constexpr int off_ctr   = 25962624;  // 2048 u32 barrier state
// end = 25966720 f16 = 49.5 MiB (unchanged)

constexpr int G8r_  = off_Xin;             // written g25, read g26 (post-inv)
constexpr int G8c_  = off_Xin + 1048576;
constexpr int G16r_ = off_Xin + 2097152;   // written g26, read g27
constexpr int G16c_ = off_Xin + 3145728;

// sc0/sc1 (LLC-direct) READ classification: only REUSED (rewritten) buffers.
// Everything else is plain L2-cached (static, or write-once + write-through).
__host__ __device__ constexpr bool dynb(int off){
  return (off >= off_P0 && off < GPr) || (off >= BA && off < off_S);
}

constexpr int P0r(int s){ return off_P0 + s*524288; }
constexpr int P0c(int s){ return off_P0 + s*524288 + 262144; }
constexpr int P1r(int s){ return off_P1 + s*524288; }
constexpr int P1c(int s){ return off_P1 + s*524288 + 262144; }
constexpr int Bb(int k){ return k==0 ? off_Dc : off_Db + (k-1)*65536; }

// ---------------- op table ----------------
struct Op {
  int type;
  int m_off, m_rstride, rows, cols;
  int k1, x1_off, x1_ks, x1_s1, x1_s2;
  int k2, x2_off, x2_ks, x2_s1, x2_s2;
  int add_off, add_ks, add_s1, add_s2;
  int bias_off; float scale;
  int y_off, y_ks, y_s1, y_s2;
  int yt_off, yt_rstride;
  int out32, tile_base;
};
constexpr int MAXOPS = 80, MAXG = 32;
struct Plan { Op ops[MAXOPS]; int gstart[MAXG+1]; int gtiles[MAXG]; int nops, ng; };

constexpr Op mko() {
  Op o{};
  o.type=0; o.m_off=0; o.m_rstride=512; o.rows=512; o.cols=512;
  o.k1=512; o.x1_off=0; o.x1_ks=512; o.x1_s1=64; o.x1_s2=0;
  o.k2=0; o.x2_off=0; o.x2_ks=512; o.x2_s1=64; o.x2_s2=0;
  o.add_off=-1; o.add_ks=512; o.add_s1=64; o.add_s2=0;
  o.bias_off=-1; o.scale=1.0f;
  o.y_off=-1; o.y_ks=512; o.y_s1=64; o.y_s2=0;
  o.yt_off=-1; o.yt_rstride=512; o.out32=0; o.tile_base=0;
  return o;
}
// 64x32 tiles
constexpr int op_ntiles(const Op& o){ return (o.rows>>6)*(o.cols>>5); }

struct Builder { Plan p{}; int nops=0, ng=0, gtile=0; };
constexpr void push(Builder& b, Op o){ o.tile_base=b.gtile; b.gtile+=op_ntiles(o); b.p.ops[b.nops++]=o; }
constexpr void endg(Builder& b){ b.p.gtiles[b.ng]=b.gtile; b.ng++; b.p.gstart[b.ng]=b.nops; b.gtile=0; }

constexpr Op SQ2(int m,int mrs,int x1c,int yc,int yr){
  Op o=mko(); o.m_off=m; o.m_rstride=mrs; o.x1_off=x1c; o.y_off=yc; o.yt_off=yr; return o; }
constexpr Op SQG(int mr,int xc,int yc,int yr){
  Op o=mko(); o.rows=1024; o.cols=1024; o.k1=1024; o.m_off=mr; o.m_rstride=1024;
  o.x1_off=xc; o.x1_ks=1024; o.y_off=yc; o.y_ks=1024; o.yt_off=yr; o.yt_rstride=1024; return o; }
constexpr Op P2S(int s){
  Op o=mko(); o.cols=4096; o.bias_off=off_b0h;
  o.k2=128; o.x2_off=off_Xin; o.x2_ks=128; o.x2_s1=512; o.x2_s2=(s-1)*64;
  o.y_off=(s&1)?BA:BB;
  if (s==1){ o.m_off=off_cat+512; o.m_rstride=640; o.k1=0; }
  else { o.m_off=off_cat; o.m_rstride=640; o.k1=512; o.x1_off=(s&1)?BB:BA; }
  return o; }
constexpr Op HS(int s){
  Op o=mko(); o.m_off=off_cat; o.m_rstride=640; o.cols=4096;
  o.k1=512; o.x1_off=(s&1)?BC:BB;
  o.k2=128; o.x2_off=off_Xin; o.x2_ks=128; o.x2_s1=512; o.x2_s2=(s-1)*64;
  o.bias_off=off_b0h; o.y_off=(s&1)?BB:BC; return o; }
constexpr Op RS(int s){
  Op o=mko(); o.cols=4096; o.bias_off=off_b1h;
  if (s==1){ o.m_off=off_catA1+512; o.m_rstride=1024; o.k1=512; o.x1_off=BB; o.y_off=BD; }
  else { o.m_off=off_catA1; o.m_rstride=1024; o.k1=512; o.x1_off=(s&1)?BA:BD;
         o.k2=512; o.x2_off=(s&1)?BB:BC; o.x2_ks=512; o.x2_s1=64; o.x2_s2=0;
         o.y_off=(s&1)?BD:BA; }
  return o; }
constexpr Op SCAN(int m,int d,int inb,int outb){
  Op o=mko(); o.m_off=m; o.cols=4096-d*64; o.x1_off=inb;
  o.add_off=inb; o.add_s2=d*64; o.y_off=outb; o.y_s2=d*64; return o; }
constexpr Op SCOPY(int d,int inb,int outb){
  Op o=mko(); o.k1=0; o.cols=d*64; o.add_off=inb; o.y_off=outb; return o; }
constexpr Op FOLDL(int m,int cols,int inb,int outb){
  Op o=mko(); o.m_off=m; o.cols=cols; o.x1_off=inb; o.x1_s1=128;
  o.add_off=inb; o.add_s1=128; o.add_s2=64; o.y_off=outb; return o; }
constexpr Op DECA(int k,int moff){
  Op o=mko(); int m=1<<k;
  o.rows=1024; o.cols=m*64; o.k1=1024; o.m_off=moff; o.m_rstride=1024;
  o.x1_off=off_S; o.x1_ks=1024; o.bias_off=Bb(k);
  o.y_off=off_S; o.y_ks=1024; o.y_s2=m*64; return o; }
constexpr Op DECB(int k,int moff){
  Op o=mko(); o.rows=1024; o.cols=64; o.k1=1024; o.m_off=moff; o.m_rstride=1024;
  o.x1_off=Bb(k); o.x1_ks=1024; o.bias_off=Bb(k);
  o.y_off=Bb(k+1); o.y_ks=1024; return o; }

constexpr Plan build_plan() {
  Builder b{}; b.p.gstart[0]=0;
  // g0: A0^2, A1^2, E, c0, P2 s1
  push(b, SQ2(off_cat,640,off_A0c,P0c(0),P0r(0)));
  push(b, SQ2(off_catA1,1024,off_A1c,P1c(0),P1r(0)));
  { Op o=mko(); o.m_off=off_cat+512; o.m_rstride=640; o.k1=128; o.x1_off=off_Wpc; o.x1_ks=128;
    o.y_off=off_Gc+512*1024; o.y_ks=1024; o.yt_off=off_Gr+512; o.yt_rstride=1024; push(b,o); } // E
  { Op o=mko(); o.m_off=off_cat+512; o.m_rstride=640; o.k1=128; o.x1_off=off_bpX; o.x1_ks=128;
    o.cols=64; o.bias_off=off_b0ah; o.scale=ALPHAF; o.y_off=off_Dc; o.y_ks=1024; push(b,o); } // c0
  push(b, P2S(1)); endg(b);
  // g1: A0^4, A1^4, F10, c1, P2 s2
  push(b, SQ2(P0r(0),512,P0c(0),P0c(1),P0r(1)));
  push(b, SQ2(P1r(0),512,P1c(0),P1c(1),P1r(1)));
  { Op o=mko(); o.m_off=off_catA1+512; o.m_rstride=1024; o.x1_off=off_A0c;
    o.y_off=off_Gc+512; o.y_ks=1024; o.yt_off=off_Gr+512*1024; o.yt_rstride=1024; push(b,o); } // F10
  { Op o=mko(); o.m_off=off_catA1+512; o.m_rstride=1024; o.x1_off=off_Dc; o.x1_ks=1024;
    o.cols=64; o.bias_off=off_b1ah; o.y_off=off_Dc+512; o.y_ks=1024; push(b,o); } // c1
  push(b, P2S(2)); endg(b);
  // g2: A0^8, A1^8, F11, P2 s3
  push(b, SQ2(P0r(1),512,P0c(1),P0c(2),P0r(2)));
  push(b, SQ2(P1r(1),512,P1c(1),P1c(2),P1r(2)));
  { Op o=mko(); o.m_off=off_catA1+512; o.m_rstride=1024; o.x1_off=off_Gc+512*1024; o.x1_ks=1024;
    o.add_off=off_A1c; o.y_off=off_Gc+512*1024+512; o.y_ks=1024;
    o.yt_off=off_Gr+512*1024+512; o.yt_rstride=1024; push(b,o); } // F11 = Wx1 E + A1
  push(b, P2S(3)); endg(b);
  // g3: A0^16, A1^16, P2 s4
  push(b, SQ2(P0r(2),512,P0c(2),P0c(0),P0r(0)));
  push(b, SQ2(P1r(2),512,P1c(2),P1c(0),P1r(0)));
  push(b, P2S(4)); endg(b);
  // g4: A0^32, A1^32, P2 s5
  push(b, SQ2(P0r(0),512,P0c(0),P0c(1),P0r(1)));
  push(b, SQ2(P1r(0),512,P1c(0),P1c(1),P1r(1)));
  push(b, P2S(5)); endg(b);
  // g5: P2 s6 + G^2
  push(b, P2S(6));
  push(b, SQG(off_Gr, off_Gc, GPc, GPr)); endg(b);
  // g6,g7: P2 s7, s8   (g = BB)
  push(b, P2S(7)); endg(b);
  push(b, P2S(8)); endg(b);
  // g8..g10: scan levels (A0^8, A0^16, A0^32) -> final in BA
  push(b, SCAN(P0r(2), 1, BB, BA)); push(b, SCOPY(1, BB, BA)); endg(b);
  push(b, SCAN(P0r(0), 2, BA, BB)); push(b, SCOPY(2, BA, BB)); endg(b);
  push(b, SCAN(P0r(1), 4, BB, BA)); push(b, SCOPY(4, BB, BA)); endg(b);
  // g11: h1 (shifted chunk-start read) -> BB
  { Op o=mko(); o.m_off=off_cat; o.m_rstride=640; o.cols=4032; o.k1=512; o.x1_off=BA;
    o.k2=128; o.x2_off=off_Xin; o.x2_ks=128; o.x2_s1=512; o.x2_s2=512;
    o.bias_off=off_b0h; o.y_off=BB; o.y_s2=64; push(b,o); }
  { Op o=mko(); o.m_off=off_cat+512; o.m_rstride=640; o.cols=64; o.k1=0;
    o.k2=128; o.x2_off=off_Xin; o.x2_ks=128; o.x2_s1=512; o.x2_s2=0;
    o.bias_off=off_b0h; o.y_off=BB; push(b,o); }
  endg(b);
  // g12..g18: {h(s+1), r(s)} for s=1..7
  for (int s=1; s<=7; ++s){ push(b, HS(s+1)); push(b, RS(s)); endg(b); }
  // g19: r8 + h0_final -> S top
  push(b, RS(8));
  { Op o=mko(); o.k1=0; o.cols=64; o.add_off=BC; o.add_s2=4032; o.scale=ALPHAF;
    o.y_off=off_S; o.y_ks=1024; push(b,o); }
  endg(b);
  // g20,g21: fold l0 (A1^8), l1 (A1^16)
  push(b, FOLDL(P1r(2), 2048, BA, BB)); endg(b);
  push(b, FOLDL(P1r(0), 1024, BB, BC)); endg(b);
  // g22: h1_final = v15 + A1^32 v14 -> S bottom
  { Op o=mko(); o.m_off=P1r(1); o.cols=64; o.x1_off=BC; o.x1_s2=896;
    o.add_off=BC; o.add_s2=960; o.scale=ALPHAF;
    o.y_off=off_S+512; o.y_ks=1024; push(b,o); }
  endg(b);
  // g23..g27: decode doubling; JIT squarings into WRITE-ONCE slots:
  // G2=GP (g5), G4=GQ (g24), G8=G8_ (g25, over dead Xin), G16=G16_ (g26)
  push(b, DECA(0, off_Gr)); push(b, DECB(0, off_Gr)); endg(b);
  push(b, DECA(1, GPr)); push(b, DECB(1, GPr)); push(b, SQG(GPr,GPc,GQc,GQr)); endg(b);
  push(b, DECA(2, GQr)); push(b, DECB(2, GQr)); push(b, SQG(GQr,GQc,G8c_,G8r_)); endg(b);
  push(b, DECA(3, G8r_)); push(b, DECB(3, G8r_)); push(b, SQG(G8r_,G8c_,G16c_,G16r_)); endg(b);
  push(b, DECA(4, G16r_)); endg(b);
  // g28: output p_t = 256 * (Wp h1_t) + bp
  { Op o=mko(); o.m_off=off_Wpr; o.rows=128; o.cols=2048; o.x1_off=off_S+512; o.x1_ks=1024;
    o.bias_off=off_bph; o.scale=RALPHAF; o.out32=1; push(b,o); }
  endg(b);
  b.p.nops=b.nops; b.p.ng=b.ng;
  return b.p;
}
static constexpr Plan h_plan = build_plan();
__device__ __constant__ Plan d_plan = h_plan;

// ---------------- async load primitives (NO trailing waitcnt) --------------
__device__ inline void issueA4(const f16* p, f16x8 (&r)[4], bool cc) {
  if (cc)
    asm volatile(
      "global_load_dwordx4 %0, %4, off sc0 sc1\n\t"
      "global_load_dwordx4 %1, %4, off offset:16 sc0 sc1\n\t"
      "global_load_dwordx4 %2, %4, off offset:32 sc0 sc1\n\t"
      "global_load_dwordx4 %3, %4, off offset:48 sc0 sc1"
      : "=&v"(r[0]), "=&v"(r[1]), "=&v"(r[2]), "=&v"(r[3])
      : "v"(p) : "memory");
  else
    asm volatile(
      "global_load_dwordx4 %0, %4, off\n\t"
      "global_load_dwordx4 %1, %4, off offset:16\n\t"
      "global_load_dwordx4 %2, %4, off offset:32\n\t"
      "global_load_dwordx4 %3, %4, off offset:48"
      : "=&v"(r[0]), "=&v"(r[1]), "=&v"(r[2]), "=&v"(r[3])
      : "v"(p) : "memory");
}
__device__ inline void issueB2(const f16* p, f16x8 (&r)[2], bool cc) {
  if (cc)
    asm volatile(
      "global_load_dwordx4 %0, %2, off sc0 sc1\n\t"
      "global_load_dwordx4 %1, %2, off offset:16 sc0 sc1"
      : "=&v"(r[0]), "=&v"(r[1]) : "v"(p) : "memory");
  else
    asm volatile(
      "global_load_dwordx4 %0, %2, off\n\t"
      "global_load_dwordx4 %1, %2, off offset:16"
      : "=&v"(r[0]), "=&v"(r[1]) : "v"(p) : "memory");
}
__device__ inline void issue_ld8(const f16* p, f16x4& r, bool cc) {
  if (cc)
    asm volatile("global_load_dwordx2 %0, %1, off sc0 sc1"
                 : "=&v"(r) : "v"(p) : "memory");
  else
    asm volatile("global_load_dwordx2 %0, %1, off"
                 : "=&v"(r) : "v"(p) : "memory");
}
__device__ inline void st8_cc(f16* p, f16x4 v) {
  asm volatile("global_store_dwordx2 %0, %1, off sc0 sc1" :: "v"(p), "v"(v) : "memory");
}
__device__ inline void st2_cc(f16* p, f16 v) {
  unsigned d = __builtin_bit_cast(unsigned short, v);
  asm volatile("global_store_short %0, %1, off sc0 sc1" :: "v"(p), "v"(d) : "memory");
}
__device__ inline unsigned ld_u32_cc(const unsigned* p) {
  unsigned r;
  asm volatile("global_load_dword %0, %1, off sc0 sc1\n\ts_waitcnt vmcnt(0)"
               : "=&v"(r) : "v"(p) : "memory");
  return r;
}
__device__ inline void st_u32_cc(unsigned* p, unsigned v) {
  asm volatile("global_store_dword %0, %1, off sc0 sc1" :: "v"(p), "v"(v) : "memory");
}
// one-time clean invalidate of this XCD's L1+L2 (no dirty kernel data: all
// dynamic stores are write-through)
__device__ inline void l2_inv() {
  asm volatile("buffer_inv sc0 sc1\n\ts_waitcnt vmcnt(0)" ::: "memory");
}

// ------- fence-free grid barrier: 32 arrival + 32 release flag lines -------
__device__ inline void grid_barrier(unsigned* ctrs, unsigned epoch) {
  __syncthreads();
  if (threadIdx.x == 0)
    __hip_atomic_fetch_add(&ctrs[(blockIdx.x & (NCTR-1))*32], 1u,
                           __ATOMIC_RELAXED, __HIP_MEMORY_SCOPE_AGENT);
  if (blockIdx.x == 0) {
    if (threadIdx.x < NCTR) {
      const unsigned tgt = epoch * (gridDim.x / NCTR);
      while (ld_u32_cc(&ctrs[threadIdx.x*32]) < tgt)
        __builtin_amdgcn_s_sleep(1);
    }
    __syncthreads();
    if (threadIdx.x < NCTR)
      st_u32_cc(&ctrs[(NCTR + threadIdx.x)*32], epoch);
  } else if (threadIdx.x == 0) {
    const unsigned fl = (NCTR + (blockIdx.x & (NCTR-1)))*32;
    while (ld_u32_cc(&ctrs[fl]) < epoch)
      __builtin_amdgcn_s_sleep(1);
  }
  // decode boundary: drop stale Xin lines before G8/G16 are written there
  if (epoch == INV_EPOCH && threadIdx.x == 0) l2_inv();
  __syncthreads();
}

// ---------------- GEMM tile machinery (64x32 tiles) ----------------
__device__ inline void chunk_srcs(const Op& o, const f16* w, int r0, int c0, int kc,
                                  const f16*& pa, const f16*& pb, bool& bcc) {
  const int tid = threadIdx.x;
  pa = w + o.m_off + (size_t)(r0 + (tid>>2)) * o.m_rstride + kc + (tid&3)*32;
  int C = c0 + (tid>>3);
  int xo, xks, xs1, xs2, xk;
  if (kc < o.k1) { xo=o.x1_off; xks=o.x1_ks; xs1=o.x1_s1; xs2=o.x1_s2; xk=kc; }
  else           { xo=o.x2_off; xks=o.x2_ks; xs1=o.x2_s1; xs2=o.x2_s2; xk=kc-o.k1; }
  int xcol = xs1*(C>>6) + (C&63) + xs2;
  pb = w + xo + (size_t)xcol*xks + xk + (tid&7)*16;
  bcc = dynb(xo);
}

__device__ inline void st_lds(f16* lsA, f16* lsB, const f16x8 (&ra)[4], const f16x8 (&rb)[2]) {
  const int tid = threadIdx.x;
  f16* da = lsA + (tid>>2)*LDA + (tid&3)*32;
#pragma unroll
  for (int i=0;i<4;++i) *(f16x8*)(da + i*8) = ra[i];
  f16* db = lsB + (tid>>3)*LDA + (tid&7)*16;
#pragma unroll
  for (int i=0;i<2;++i) *(f16x8*)(db + i*8) = rb[i];
}

__device__ inline void mfma_lds(const f16* lsA, const f16* lsB, f32x4 (&acc)[2]) {
  const int tid = threadIdx.x, lane = tid & 63, wid = tid >> 6;
  const int ko = (lane >> 4) * 8, rl = lane & 15;
#pragma unroll
  for (int kb = 0; kb < 4; ++kb) {
    f16x8 a = *(const f16x8*)(lsA + (wid*16 + rl) * LDA + kb*32 + ko);
#pragma unroll
    for (int n = 0; n < 2; ++n) {
      f16x8 bb = *(const f16x8*)(lsB + (n*16 + rl) * LDA + kb*32 + ko);
      acc[n] = __builtin_amdgcn_mfma_f32_16x16x32_f16(a, bb, acc[n], 0, 0, 0);
    }
  }
}

// Raw-barrier chunk step (T4): lgkmcnt-only around s_barrier, counted vmcnt
// keeps up to 2 newer chunks' loads in flight ACROSS the barriers.
#define CH_STEP(c_, raX, rbX)                                                  \
  do {                                                                         \
    asm volatile("s_waitcnt lgkmcnt(0)" ::: "memory");                         \
    __builtin_amdgcn_s_barrier();                                              \
    __builtin_amdgcn_sched_barrier(0);                                         \
    int rem_ = nch - 1 - (c_);                                                 \
    if (rem_ >= 2)      asm volatile("s_waitcnt vmcnt(12)" ::: "memory");      \
    else if (rem_ == 1) asm volatile("s_waitcnt vmcnt(6)"  ::: "memory");      \
    else                asm volatile("s_waitcnt vmcnt(0)"  ::: "memory");      \
    __builtin_amdgcn_sched_barrier(0);                                         \
    st_lds(lsA, lsB, raX, rbX);                                                \
    asm volatile("s_waitcnt lgkmcnt(0)" ::: "memory");                         \
    __builtin_amdgcn_s_barrier();                                              \
    __builtin_amdgcn_sched_barrier(0);                                         \
    if ((c_) + 3 < nch) {                                                      \
      chunk_srcs(o, w, r0, c0, ((c_)+3)*128, pa, pb, bcc);                     \
      issueA4(pa, raX, mcc); issueB2(pb, rbX, bcc);                            \
    }                                                                          \
    mfma_lds(lsA, lsB, acc);                                                   \
  } while (0)

__device__ void run_tile(const Op& o, int local, f16* w, float* out, f16* lsA, f16* lsB) {
  int nct = o.cols >> 5;
  int rg = local / nct, ct = local - rg * nct;
  int r0 = rg << 6, c0 = ct << 5;
  const bool mcc = dynb(o.m_off);
  const bool addcc = dynb(o.add_off);
  const bool biascc = dynb(o.bias_off);
  f32x4 acc[2];
  acc[0] = f32x4{0.f,0.f,0.f,0.f}; acc[1] = f32x4{0.f,0.f,0.f,0.f};
  int nch = (o.k1 + o.k2) >> 7;
  if (nch > 0) {
    const f16 *pa, *pb; bool bcc;
    f16x8 ra0[4], rb0[2], ra1[4], rb1[2], ra2[4], rb2[2];
    chunk_srcs(o, w, r0, c0, 0, pa, pb, bcc);
    issueA4(pa, ra0, mcc); issueB2(pb, rb0, bcc);
    if (nch > 1) { chunk_srcs(o, w, r0, c0, 128, pa, pb, bcc);
                   issueA4(pa, ra1, mcc); issueB2(pb, rb1, bcc); }
    if (nch > 2) { chunk_srcs(o, w, r0, c0, 256, pa, pb, bcc);
                   issueA4(pa, ra2, mcc); issueB2(pb, rb2, bcc); }
    for (int c = 0; c < nch; c += 3) {
      CH_STEP(c, ra0, rb0);
      if (c + 1 < nch) CH_STEP(c+1, ra1, rb1);
      if (c + 2 < nch) CH_STEP(c+2, ra2, rb2);
    }
  }
  const int tid = threadIdx.x, lane = tid & 63, wid = tid >> 6;
  const int q4 = (lane >> 4) * 4, cl = lane & 15;
  const int r = r0 + wid*16 + q4;
  // ---- batched epilogue operand loads (issue all async, wait once) ----
  f16x4 addv[2], biasv;
  bool pend = false;
  if (o.add_off >= 0) {
#pragma unroll
    for (int n = 0; n < 2; ++n) {
      int C = c0 + n*16 + cl;
      int acol = o.add_s1 * (C>>6) + (C&63) + o.add_s2;
      const f16* ap = w + o.add_off + (size_t)acol * o.add_ks + r;
      issue_ld8(ap, addv[n], addcc); pend = true;
    }
  }
  if (o.bias_off >= 0) {
    const f16* bp2 = w + o.bias_off + r;
    issue_ld8(bp2, biasv, biascc); pend = true;
  }
  if (pend) asm volatile("s_waitcnt vmcnt(0)" ::: "memory");
#pragma unroll
  for (int n = 0; n < 2; ++n) {
    int C = c0 + n*16 + cl;
    f32x4 v = acc[n];
    if (o.add_off >= 0) {
      v[0]+=(float)addv[n][0]; v[1]+=(float)addv[n][1];
      v[2]+=(float)addv[n][2]; v[3]+=(float)addv[n][3];
    }
    v[0]*=o.scale; v[1]*=o.scale; v[2]*=o.scale; v[3]*=o.scale;
    if (o.bias_off >= 0) {
      v[0]+=(float)biasv[0]; v[1]+=(float)biasv[1];
      v[2]+=(float)biasv[2]; v[3]+=(float)biasv[3];
    }
    if (o.y_off >= 0) {
      int ycol = o.y_s1 * (C>>6) + (C&63) + o.y_s2;
      f16* yp = w + o.y_off + (size_t)ycol * o.y_ks + r;
      f16x4 h; h[0]=(f16)v[0]; h[1]=(f16)v[1]; h[2]=(f16)v[2]; h[3]=(f16)v[3];
      st8_cc(yp, h);
    }
    if (o.yt_off >= 0) {
      f16* tp = w + o.yt_off;
      st2_cc(tp + (size_t)(r+0)*o.yt_rstride + C, (f16)v[0]);
      st2_cc(tp + (size_t)(r+1)*o.yt_rstride + C, (f16)v[1]);
      st2_cc(tp + (size_t)(r+2)*o.yt_rstride + C, (f16)v[2]);
      st2_cc(tp + (size_t)(r+3)*o.yt_rstride + C, (f16)v[3]);
    }
    if (o.out32) {
      float* op2 = out + (size_t)(C & 63) * (NF*DIN) + (size_t)(C >> 6) * DIN + r;
      op2[0]=v[0]; op2[1]=v[1]; op2[2]=v[2]; op2[3]=v[3];
    }
  }
}

__global__ __launch_bounds__(256, 4) void rnn_main(f16* w, float* out) {
  __shared__ f16 lsA[64*LDA];
  __shared__ f16 lsB[32*LDA];
  unsigned* ctrs = (unsigned*)(w + off_ctr);
  const int wg = blockIdx.x;
  const int stride = gridDim.x;
  const int ng = d_plan.ng;
  for (int g = 0; g < ng; ++g) {
    int o0 = d_plan.gstart[g], o1 = d_plan.gstart[g+1];
    int gtot = d_plan.gtiles[g];
    for (int t = wg; t < gtot; t += stride) {
      int oi = o0;
      while (oi + 1 < o1 && t >= d_plan.ops[oi+1].tile_base) ++oi;
      run_tile(d_plan.ops[oi], t - d_plan.ops[oi].tile_base, w, out, lsA, lsB);
    }
    grid_barrier(ctrs, (unsigned)(g + 1));
  }
}

// ---------------- prep ----------------
__global__ void rnn_prep(f16* w, const float* X, const float* Wx0, const float* b0,
    const float* Wh0, const float* d0p, const float* Wx1, const float* b1,
    const float* Wh1, const float* d1p, const float* Wp, const float* bp)
{
  const float d0 = d0p[0], d1 = d1p[0];
  const long n0=512L*640, n1=512L*1024, n2=(long)SZ, n3=(long)SZ, n4=128L*512, n5=512L*128,
             n6=(long)SZ, n7=(long)SZ, n8=32768L*128, n9=512, n10=512, n11=512, n12=512,
             n13=128, n14=64L*128, n15=2048;
  const long total = n0+n1+n2+n3+n4+n5+n6+n7+n8+n9+n10+n11+n12+n13+n14+n15;
  for (long idx = (long)blockIdx.x*blockDim.x + threadIdx.x; idx < total;
       idx += (long)gridDim.x*blockDim.x) {
    long j = idx;
    if (j < n0) { int r=(int)(j/640), c=(int)(j%640);
      w[off_cat+j] = (f16)(c<512 ? d0*Wh0[(long)r*512+c] : Wx0[(long)r*128+(c-512)]); continue; }
    j -= n0;
    if (j < n1) { int r=(int)(j>>10), c=(int)(j&1023);
      w[off_catA1+j] = (f16)(c<512 ? d1*Wh1[(long)r*512+c] : Wx1[(long)r*512+(c-512)]); continue; }
    j -= n1;
    if (j < n2) { int c=(int)(j>>9), r=(int)(j&511); w[off_A0c+j] = (f16)(d0*Wh0[(long)r*512+c]); continue; }
    j -= n2;
    if (j < n3) { int c=(int)(j>>9), r=(int)(j&511); w[off_A1c+j] = (f16)(d1*Wh1[(long)r*512+c]); continue; }
    j -= n3;
    if (j < n4) { w[off_Wpr+j] = (f16)Wp[j]; continue; }
    j -= n4;
    if (j < n5) { int c=(int)(j>>7), k=(int)(j&127); w[off_Wpc+j] = (f16)Wp[(long)k*512+c]; continue; }
    j -= n5;
    if (j < n6) { int r=(int)(j>>9), c=(int)(j&511);
      w[off_Gr + (long)r*1024 + c] = (f16)(d0*Wh0[(long)r*512+c]); continue; }
    j -= n6;
    if (j < n7) { int c=(int)(j>>9), r=(int)(j&511);
      w[off_Gc + (long)c*1024 + r] = (f16)(d0*Wh0[(long)r*512+c]); continue; }
    j -= n7;
    if (j < n8) { int col=(int)(j>>7), d=(int)(j&127); int t=col>>6, bb=col&63;
      w[off_Xin+j] = (f16)X[((long)bb<<16) + ((long)t<<7) + d]; continue; }
    j -= n8;
    if (j < n9) { w[off_b0h+j] = (f16)b0[j]; continue; }  j -= n9;
    if (j < n10){ w[off_b1h+j] = (f16)b1[j]; continue; }  j -= n10;
    if (j < n11){ w[off_b0ah+j] = (f16)(ALPHAF*b0[j]); continue; }  j -= n11;
    if (j < n12){ w[off_b1ah+j] = (f16)(ALPHAF*b1[j]); continue; }  j -= n12;
    if (j < n13){ w[off_bph+j] = (f16)bp[j]; continue; }  j -= n13;
    if (j < n14){ int k=(int)(j&127); w[off_bpX+j] = (f16)bp[k]; continue; }  j -= n14;
    ((unsigned*)(w + off_ctr))[j] = 0u;
  }
}

extern "C" void kernel_launch(void* const* d_in, const int* in_sizes, int n_in,
                              void* d_out, int out_size, void* d_ws, size_t ws_size,
                              hipStream_t stream) {
  (void)in_sizes; (void)n_in; (void)out_size; (void)ws_size; // needs ~50 MB ws
  f16* w = (f16*)d_ws;
  hipLaunchKernelGGL(rnn_prep, dim3(2048), dim3(256), 0, stream,
      w,
      (const float*)d_in[0], (const float*)d_in[1], (const float*)d_in[2],
      (const float*)d_in[3], (const float*)d_in[4], (const float*)d_in[5],
      (const float*)d_in[6], (const float*)d_in[7], (const float*)d_in[8],
      (const float*)d_in[9], (const float*)d_in[10]);
  float* outp = (float*)d_out;
  void* kargs[] = { (void*)&w, (void*)&outp };
  // deterministic grid selection: up to 4 blocks/CU, halving fallback
  int nb = 0;
  hipError_t qe = hipOccupancyMaxActiveBlocksPerMultiprocessor(
      &nb, (const void*)rnn_main, 256, 0);
  int bpc = (qe == hipSuccess && nb >= 1) ? (nb >= 4 ? 4 : (nb >= 2 ? 2 : 1)) : 1;
  int grid = 256 * bpc;
  while (true) {
    hipError_t le = hipLaunchCooperativeKernel((const void*)rnn_main, dim3(grid),
                                               dim3(256), kargs, 0, stream);
    if (le == hipSuccess || grid <= 256) break;
    grid >>= 1;
  }
}